// Round 8
// baseline (1097.605 us; speedup 1.0000x reference)
//
#include <hip/hip_runtime.h>
#include <math.h>

#define BATCH 4096
#define HID   1024
#define KDIM  1024
#define NSTEP 15
#define KV    3072      // virtual K: [A_hi·B_hi | A_hi·B_lo | A_lo·B_hi]
#define NCHUNK (KV / 64)
#define NSEC  (KV / 16) // 192 k16-sections
#define NT    (HID / 32)// 32 n-tiles

// Step GEMM: 128 threads = 2 waves; block tile 64(M) x 128(N); wave tile 64x64
// via 2x2 frags of mfma_f32_32x32x16_f16. B prepacked in fragment order ->
// direct coalesced global loads (no LDS). A staged in XOR-swizzled LDS
// (conflict-free b128 r/w), double-buffered, 1 barrier/chunk.

typedef _Float16 half8 __attribute__((ext_vector_type(8)));
typedef float floatx16 __attribute__((ext_vector_type(16)));

__device__ __forceinline__ size_t b3addr(int n, int kv) {
    // [ntile][section][lane][8]: lane = (n&31) + 32*((kv>>3)&1)
    return ((size_t)((n >> 5) * NSEC + (kv >> 4))) * 512 +
           (size_t)(((n & 31) + 32 * ((kv >> 3) & 1)) * 8 + (kv & 7));
}

// Pack W_ih/W_hh into B-fragment order (hi,lo,hi thirds), split inputs/hidden
// into f16 hi/lo, init lists/accums/flagcol.
__global__ __launch_bounds__(256) void setup_kernel(
    const float* __restrict__ W_ih, const float* __restrict__ W_hh,
    const float* __restrict__ inputs, const float* __restrict__ hidden,
    _Float16* __restrict__ B3ih, _Float16* __restrict__ B3hh,
    _Float16* __restrict__ Ihi, _Float16* __restrict__ Ilo,
    _Float16* __restrict__ Hhi, _Float16* __restrict__ Hlo,
    float* __restrict__ flagcol, int* __restrict__ list0, int* __restrict__ counts,
    float* __restrict__ halt_accum, float* __restrict__ tot_rem) {
    size_t idx = (size_t)blockIdx.x * 256 + threadIdx.x;   // grid 16384 -> 4M
    {
        float x = inputs[idx];
        _Float16 h = (_Float16)x;
        Ihi[idx] = h; Ilo[idx] = (_Float16)(x - (float)h);
        float y = hidden[idx];
        _Float16 g = (_Float16)y;
        Hhi[idx] = g; Hlo[idx] = (_Float16)(y - (float)g);
    }
    if (idx < (size_t)KDIM * KDIM) {
        int n = (int)(idx >> 10), k = (int)(idx & 1023);
        float w = W_hh[idx];
        _Float16 hi = (_Float16)w;
        _Float16 lo = (_Float16)(w - (float)hi);
        B3hh[b3addr(n, k)] = hi;
        B3hh[b3addr(n, 1024 + k)] = lo;
        B3hh[b3addr(n, 2048 + k)] = hi;
        float w2 = W_ih[(size_t)n * 1025 + k];
        _Float16 hi2 = (_Float16)w2;
        _Float16 lo2 = (_Float16)(w2 - (float)hi2);
        B3ih[b3addr(n, k)] = hi2;
        B3ih[b3addr(n, 1024 + k)] = lo2;
        B3ih[b3addr(n, 2048 + k)] = hi2;
    }
    if (idx < BATCH) { list0[idx] = idx; halt_accum[idx] = 0.f; tot_rem[idx] = 0.f; }
    if (idx < KDIM) flagcol[idx] = W_ih[idx * 1025 + 1024];
    if (idx < 16) counts[idx] = (idx == 0) ? BATCH : 0;
}

// mode 0: xout[row] = A @ B^T + bias (fp32)
// mode 1: h = tanh(acc + xbase + flag*flagcol + bias); store h as f16 hi/lo
__global__ __launch_bounds__(128) void mfma_step_kernel(
    const _Float16* __restrict__ Ahi, const _Float16* __restrict__ Alo,
    const _Float16* __restrict__ B3f, const float* __restrict__ bias,
    const float* __restrict__ xbase, const float* __restrict__ flagcol, float flag,
    const int* __restrict__ list, const int* __restrict__ pcount,
    _Float16* __restrict__ houthi, _Float16* __restrict__ houtlo,
    float* __restrict__ xout, int mode) {
    int count = pcount ? *pcount : BATCH;
    int row0 = blockIdx.x * 64;
    if (row0 >= count) return;
    int col0 = blockIdx.y * 128;

    __shared__ _Float16 Asm[2][64 * 64];   // XOR-swizzled: no padding, 16 KB

    int t = threadIdx.x;
    int lane = t & 63, w = t >> 6;
    int l31 = lane & 31, l5 = lane >> 5;

    // A staging map: 64 rows x 8 half8-groups = 512 ops, 4/thread
    int asl[4]; size_t aoff[4];
#pragma unroll
    for (int l = 0; l < 4; l++) {
        int q = t + l * 128;
        int r = q >> 3, qk = q & 7;
        asl[l] = r * 64 + ((qk ^ (r & 7)) << 3);       // swizzled LDS slot
        int rr = row0 + r;
        int g = (rr < count) ? (list ? list[rr] : rr) : 0;
        aoff[l] = (size_t)g * KDIM + (size_t)(qk << 3);
    }

    // B fragment base pointers: wave w covers n-tiles nt0, nt0+1
    const half8* B8 = (const half8*)B3f;
    int nt0 = (col0 >> 5) + w * 2;
    const half8* Bp0 = B8 + (size_t)nt0 * NSEC * 64;
    const half8* Bp1 = B8 + (size_t)(nt0 + 1) * NSEC * 64;

    floatx16 acc[2][2];
#pragma unroll
    for (int i = 0; i < 2; i++)
#pragma unroll
        for (int j = 0; j < 2; j++)
#pragma unroll
            for (int r = 0; r < 16; r++) acc[i][j][r] = 0.f;

    // preload chunk 0 into buf 0
    half8 av[4];
#pragma unroll
    for (int l = 0; l < 4; l++) av[l] = *(const half8*)(Ahi + aoff[l]);
#pragma unroll
    for (int l = 0; l < 4; l++) *(half8*)(&Asm[0][asl[l]]) = av[l];
    __syncthreads();

    int p = 0;
    for (int it = 0; it < NCHUNK; it++) {
        if (it + 1 < NCHUNK) {                          // global prefetch chunk it+1
            int k0v = (it + 1) << 6;
            const _Float16* Asrc = (k0v < 2048) ? Ahi : Alo;   // segs [hi,hi,lo]
            size_t kp = (size_t)(k0v & 1023);
#pragma unroll
            for (int l = 0; l < 4; l++) av[l] = *(const half8*)(Asrc + aoff[l] + kp);
        }
#pragma unroll
        for (int s = 0; s < 4; s++) {
            int sg = it * 4 + s;
            int gl = s * 2 + l5;                        // logical half8 group in row
            int ga = (gl ^ (l31 & 7)) << 3;             // swizzled
            half8 a0 = *(const half8*)(&Asm[p][l31 * 64 + ga]);
            half8 a1 = *(const half8*)(&Asm[p][(32 + l31) * 64 + ga]);
            half8 b0 = Bp0[(size_t)sg * 64 + lane];
            half8 b1 = Bp1[(size_t)sg * 64 + lane];
            acc[0][0] = __builtin_amdgcn_mfma_f32_32x32x16_f16(a0, b0, acc[0][0], 0, 0, 0);
            acc[0][1] = __builtin_amdgcn_mfma_f32_32x32x16_f16(a0, b1, acc[0][1], 0, 0, 0);
            acc[1][0] = __builtin_amdgcn_mfma_f32_32x32x16_f16(a1, b0, acc[1][0], 0, 0, 0);
            acc[1][1] = __builtin_amdgcn_mfma_f32_32x32x16_f16(a1, b1, acc[1][1], 0, 0, 0);
        }
        if (it + 1 < NCHUNK) {
            int q = p ^ 1;
#pragma unroll
            for (int l = 0; l < 4; l++) *(half8*)(&Asm[q][asl[l]]) = av[l];
        }
        __syncthreads();
        p ^= 1;
    }

    // C/D layout (32x32): col=lane&31, row=(reg&3)+8*(reg>>2)+4*(lane>>5)  [m74/m101]
#pragma unroll
    for (int fi = 0; fi < 2; fi++) {
#pragma unroll
        for (int r = 0; r < 16; r++) {
            int rowid = (r & 3) + 8 * (r >> 2) + 4 * l5;
            int grd = row0 + fi * 32 + rowid;
            if (grd >= count) continue;
            int g = list ? list[grd] : grd;
#pragma unroll
            for (int fj = 0; fj < 2; fj++) {
                int c = col0 + w * 64 + fj * 32 + l31;
                float v = acc[fi][fj][r];
                if (mode == 0) {
                    xout[(size_t)g * KDIM + c] = v + bias[c];
                } else {
                    v += xbase[(size_t)g * KDIM + c] + flag * flagcol[c] + bias[c];
                    v = tanhf(v);
                    _Float16 hi = (_Float16)v;
                    houthi[(size_t)g * KDIM + c] = hi;
                    houtlo[(size_t)g * KDIM + c] = (_Float16)(v - (float)hi);
                }
            }
        }
    }
}

// One wave per active row: halt logit (h = hi+lo), sigmoid, halting state
// machine, tot_h accumulation, next-list compaction.
__global__ __launch_bounds__(256) void halt_kernel(
    const _Float16* __restrict__ Hhi, const _Float16* __restrict__ Hlo,
    const float* __restrict__ W_halt, const float* __restrict__ b_halt,
    const int* __restrict__ list, const int* __restrict__ pcount,
    int* __restrict__ list_next, int* __restrict__ pcount_next,
    float* __restrict__ halt_accum, float* __restrict__ tot_rem,
    float* __restrict__ tot_h, float* __restrict__ steps_out,
    int stepnum, int first) {
    int count = *pcount;
    int wid = threadIdx.x >> 6, lane = threadIdx.x & 63;
    int r = blockIdx.x * 4 + wid;
    if (r >= count) return;
    int row = list[r];
    const _Float16* hh = Hhi + (size_t)row * HID;
    const _Float16* hl = Hlo + (size_t)row * HID;

    float hv[16];
    float dot = 0.f;
#pragma unroll
    for (int q = 0; q < 2; q++) {
        int c = q * 512 + lane * 8;
        half8 h8 = *(const half8*)(hh + c);
        half8 l8 = *(const half8*)(hl + c);
#pragma unroll
        for (int j = 0; j < 8; j++) {
            float v = (float)h8[j] + (float)l8[j];
            hv[q * 8 + j] = v;
            dot += v * W_halt[c + j];
        }
    }
#pragma unroll
    for (int off = 32; off > 0; off >>= 1) dot += __shfl_down(dot, off);

    float combined = 0.f;
    if (lane == 0) {
        float p = 1.f / (1.f + expf(-(dot + b_halt[0])));
        float S = halt_accum[row] + p;
        halt_accum[row] = S;
        tot_rem[row] += p;
        bool ending = (S + p) > 0.99f;      // budget = 1 - PONDER_EPS
        if (ending) {
            combined = p + (1.f - S);
            steps_out[row] = (float)stepnum;
        } else {
            combined = p;
            int idx = atomicAdd(pcount_next, 1);
            list_next[idx] = row;
        }
    }
    combined = __shfl(combined, 0);

    float* th = tot_h + (size_t)row * HID;
#pragma unroll
    for (int q = 0; q < 2; q++) {
        int c = q * 512 + lane * 8;
#pragma unroll
        for (int j = 0; j < 8; j += 4) {
            float4 ov;
            if (first) {
                ov = make_float4(0.f, 0.f, 0.f, 0.f);
            } else {
                ov = *(const float4*)(th + c + j);
            }
            ov.x += combined * hv[q * 8 + j + 0];
            ov.y += combined * hv[q * 8 + j + 1];
            ov.z += combined * hv[q * 8 + j + 2];
            ov.w += combined * hv[q * 8 + j + 3];
            *(float4*)(th + c + j) = ov;
        }
    }
}

// blocks 0..1023: survivors get (1 - halt_accum) * h_final, steps = 16.
// block 1024: ponder reduction.
__global__ __launch_bounds__(256) void epilogue_kernel(
    const _Float16* __restrict__ Hhi, const _Float16* __restrict__ Hlo,
    const int* __restrict__ list, const int* __restrict__ pcount,
    const float* __restrict__ halt_accum, const float* __restrict__ tot_rem,
    float* __restrict__ tot_h, float* __restrict__ steps_out,
    float* __restrict__ ponder) {
    if (blockIdx.x == 1024) {
        __shared__ float red[4];
        int t = threadIdx.x;
        float v = 0.f;
#pragma unroll
        for (int i = 0; i < 16; i++) v += tot_rem[t + i * 256];
#pragma unroll
        for (int off = 32; off > 0; off >>= 1) v += __shfl_down(v, off);
        int lane = t & 63, wid = t >> 6;
        if (lane == 0) red[wid] = v;
        __syncthreads();
        if (t == 0) ponder[0] = (red[0] + red[1] + red[2] + red[3]) * (-0.01f / 4096.f);
        return;
    }
    int count = *pcount;
    int wid = threadIdx.x >> 6, lane = threadIdx.x & 63;
    int r = blockIdx.x * 4 + wid;
    if (r >= count) return;
    int row = list[r];
    float cmb = 1.f - halt_accum[row];
    if (lane == 0) steps_out[row] = 16.f;
    const _Float16* hh = Hhi + (size_t)row * HID;
    const _Float16* hl = Hlo + (size_t)row * HID;
    float* th = tot_h + (size_t)row * HID;
#pragma unroll
    for (int q = 0; q < 2; q++) {
        int c = q * 512 + lane * 8;
        half8 h8 = *(const half8*)(hh + c);
        half8 l8 = *(const half8*)(hl + c);
#pragma unroll
        for (int j = 0; j < 8; j += 4) {
            float4 ov = *(const float4*)(th + c + j);
            ov.x += cmb * ((float)h8[j + 0] + (float)l8[j + 0]);
            ov.y += cmb * ((float)h8[j + 1] + (float)l8[j + 1]);
            ov.z += cmb * ((float)h8[j + 2] + (float)l8[j + 2]);
            ov.w += cmb * ((float)h8[j + 3] + (float)l8[j + 3]);
            *(float4*)(th + c + j) = ov;
        }
    }
}

extern "C" void kernel_launch(void* const* d_in, const int* in_sizes, int n_in,
                              void* d_out, int out_size, void* d_ws, size_t ws_size,
                              hipStream_t stream) {
    const float* inputs = (const float*)d_in[0];
    const float* hidden = (const float*)d_in[1];
    const float* W_ih   = (const float*)d_in[2];
    const float* b_ih   = (const float*)d_in[3];
    const float* W_hh   = (const float*)d_in[4];
    const float* b_hh   = (const float*)d_in[5];
    const float* W_halt = (const float*)d_in[6];
    const float* b_halt = (const float*)d_in[7];
    float* out = (float*)d_out;

    float* ws = (float*)d_ws;
    const size_t NM = (size_t)BATCH * HID;               // 4M elements
    float* xbase = ws;                                   // 4M f32
    _Float16* B3ih = (_Float16*)(xbase + NM);            // HID*KV halfs
    _Float16* B3hh = B3ih + (size_t)HID * KV;
    _Float16* Ahi0 = B3hh + (size_t)HID * KV;            // 4M halfs each
    _Float16* Alo0 = Ahi0 + NM;
    _Float16* Ahi1 = Alo0 + NM;
    _Float16* Alo1 = Ahi1 + NM;
    float* flagcol = (float*)(Alo1 + NM);                // 1024
    float* halt_accum = flagcol + KDIM;                  // 4096
    float* tot_rem = halt_accum + BATCH;                 // 4096
    int* list0 = (int*)(tot_rem + BATCH);                // 4096
    int* list1 = list0 + BATCH;                          // 4096
    int* counts = list1 + BATCH;                         // 16

    _Float16* Ahi[2] = {Ahi0, Ahi1};
    _Float16* Alo[2] = {Alo0, Alo1};
    int* lists[2] = {list0, list1};

    float* tot_h = out;
    float* ponder = out + NM;
    float* steps_out = ponder + 1;

    // setup: pack B frags, split inputs -> buf1 (dead after x_base), hidden -> buf0
    setup_kernel<<<16384, 256, 0, stream>>>(W_ih, W_hh, inputs, hidden,
                                            B3ih, B3hh, Ahi1, Alo1, Ahi0, Alo0,
                                            flagcol, list0, counts, halt_accum, tot_rem);

    // x_base = inputs @ W_ih[:, :-1].T + b_ih
    mfma_step_kernel<<<dim3(64, 8), 128, 0, stream>>>(
        Ahi1, Alo1, B3ih, b_ih, nullptr, nullptr, 0.f, nullptr, nullptr,
        nullptr, nullptr, xbase, 0);

    for (int t = 0; t < NSTEP; t++) {
        mfma_step_kernel<<<dim3(64, 8), 128, 0, stream>>>(
            Ahi[t & 1], Alo[t & 1], B3hh, b_hh, xbase, flagcol,
            (t == 0) ? 1.f : 0.f, lists[t & 1], counts + t,
            Ahi[(t + 1) & 1], Alo[(t + 1) & 1], nullptr, 1);
        halt_kernel<<<1024, 256, 0, stream>>>(Ahi[(t + 1) & 1], Alo[(t + 1) & 1],
                                              W_halt, b_halt,
                                              lists[t & 1], counts + t,
                                              lists[(t + 1) & 1], counts + t + 1,
                                              halt_accum, tot_rem, tot_h, steps_out,
                                              t + 1, (t == 0) ? 1 : 0);
    }
    epilogue_kernel<<<1025, 256, 0, stream>>>(Ahi[0], Alo[0], lists[1], counts + 15,
                                              halt_accum, tot_rem, tot_h, steps_out, ponder);
}

// Round 9
// 862.634 us; speedup vs baseline: 1.2724x; 1.2724x over previous
//
#include <hip/hip_runtime.h>
#include <math.h>

#define BATCH 4096
#define HID   1024
#define KDIM  1024
#define NSTEP 15
#define KV    3072      // virtual K: [A_hi·B_hi | A_hi·B_lo | A_lo·B_hi]
#define NCHUNK (KV / 64)
#define NSEC  (KV / 16) // 192 k16-sections

// Step GEMM: 512 threads = 8 waves (2M x 4N); block tile 128M x 128N; wave
// tile 64x32 = 2 m-frags of mfma_f32_32x32x16_f16, nj=1.
// A: global_load_lds DMA directly into MFMA-fragment-order LDS ([mt][sec][lane*8]),
//    double-buffered, per-lane gather through `list`. Frag reads lane-linear b128.
// B: prepacked fragment-order global (R8-validated), register-prefetched.

typedef _Float16 half8 __attribute__((ext_vector_type(8)));
typedef float floatx16 __attribute__((ext_vector_type(16)));

__device__ __forceinline__ size_t b3addr(int n, int kv) {
    // [ntile][section][lane = (n&31) + 32*((kv>>3)&1)][kv&7]
    return ((size_t)((n >> 5) * NSEC + (kv >> 4))) * 512 +
           (size_t)(((n & 31) + 32 * ((kv >> 3) & 1)) * 8 + (kv & 7));
}

__device__ __forceinline__ void dma16(const _Float16* g, _Float16* l) {
    __builtin_amdgcn_global_load_lds(
        (const __attribute__((address_space(1))) unsigned int*)g,
        (__attribute__((address_space(3))) unsigned int*)l, 16, 0, 0);
}

// Pack W_ih/W_hh into B-fragment order (hi,lo,hi thirds), split inputs/hidden
// into f16 hi/lo, init lists/accums/flagcol.
__global__ __launch_bounds__(256) void setup_kernel(
    const float* __restrict__ W_ih, const float* __restrict__ W_hh,
    const float* __restrict__ inputs, const float* __restrict__ hidden,
    _Float16* __restrict__ B3ih, _Float16* __restrict__ B3hh,
    _Float16* __restrict__ Ihi, _Float16* __restrict__ Ilo,
    _Float16* __restrict__ Hhi, _Float16* __restrict__ Hlo,
    float* __restrict__ flagcol, int* __restrict__ list0, int* __restrict__ counts,
    float* __restrict__ halt_accum, float* __restrict__ tot_rem) {
    size_t idx = (size_t)blockIdx.x * 256 + threadIdx.x;   // grid 16384 -> 4M
    {
        float x = inputs[idx];
        _Float16 h = (_Float16)x;
        Ihi[idx] = h; Ilo[idx] = (_Float16)(x - (float)h);
        float y = hidden[idx];
        _Float16 g = (_Float16)y;
        Hhi[idx] = g; Hlo[idx] = (_Float16)(y - (float)g);
    }
    if (idx < (size_t)KDIM * KDIM) {
        int n = (int)(idx >> 10), k = (int)(idx & 1023);
        float w = W_hh[idx];
        _Float16 hi = (_Float16)w;
        _Float16 lo = (_Float16)(w - (float)hi);
        B3hh[b3addr(n, k)] = hi;
        B3hh[b3addr(n, 1024 + k)] = lo;
        B3hh[b3addr(n, 2048 + k)] = hi;
        float w2 = W_ih[(size_t)n * 1025 + k];
        _Float16 hi2 = (_Float16)w2;
        _Float16 lo2 = (_Float16)(w2 - (float)hi2);
        B3ih[b3addr(n, k)] = hi2;
        B3ih[b3addr(n, 1024 + k)] = lo2;
        B3ih[b3addr(n, 2048 + k)] = hi2;
    }
    if (idx < BATCH) { list0[idx] = idx; halt_accum[idx] = 0.f; tot_rem[idx] = 0.f; }
    if (idx < KDIM) flagcol[idx] = W_ih[idx * 1025 + 1024];
    if (idx < 16) counts[idx] = (idx == 0) ? BATCH : 0;
}

// mode 0: xout[row] = A @ B^T + bias (fp32)
// mode 1: h = tanh(acc + xbase + flag*flagcol + bias); store h as f16 hi/lo
__global__ __launch_bounds__(512, 2) void mfma_step_kernel(
    const _Float16* __restrict__ Ahi, const _Float16* __restrict__ Alo,
    const _Float16* __restrict__ B3f, const float* __restrict__ bias,
    const float* __restrict__ xbase, const float* __restrict__ flagcol, float flag,
    const int* __restrict__ list, const int* __restrict__ pcount,
    _Float16* __restrict__ houthi, _Float16* __restrict__ houtlo,
    float* __restrict__ xout, int mode) {
    int count = pcount ? *pcount : BATCH;
    int row0 = blockIdx.x * 128;
    if (row0 >= count) return;
    int col0 = blockIdx.y * 128;

    __shared__ _Float16 Asm[2][8192];      // [mt(4)][sec(4)][512] frag-order, 16KB x2

    int t = threadIdx.x;
    int lane = t & 63, w = t >> 6;
    int l31 = lane & 31, l5 = lane >> 5;
    int wm = w & 1, wn = w >> 1;           // compute: rows wm*64, cols col0+wn*32

    // DMA duty: wave w stages m-tile (w>>1), sections {2*(w&1), 2*(w&1)+1}
    int dmt = w >> 1;
    int ds0 = 2 * (w & 1);
    int rr = row0 + dmt * 32 + l31;
    int gA = (rr < count) ? (list ? list[rr] : rr) : 0;
    size_t abase = (size_t)gA * KDIM + (size_t)(l5 * 8);

    // B fragment pointer (half8 units): compute col-tile for this wave
    const half8* B8 = (const half8*)B3f;
    int ct = (col0 >> 5) + wn;
    size_t bbase = (size_t)ct * (NSEC * 64) + lane;

    floatx16 acc[2];
#pragma unroll
    for (int i = 0; i < 2; i++)
#pragma unroll
        for (int r = 0; r < 16; r++) acc[i][r] = 0.f;

    half8 bcur[4], bnxt[4];

    // prologue: chunk 0 (Ahi, kp=0)
    dma16(Ahi + abase + ds0 * 16, &Asm[0][dmt * 2048 + ds0 * 512]);
    dma16(Ahi + abase + (ds0 + 1) * 16, &Asm[0][dmt * 2048 + (ds0 + 1) * 512]);
#pragma unroll
    for (int s = 0; s < 4; s++) bcur[s] = B8[bbase + (size_t)s * 64];
    __syncthreads();

    int p = 0;
    int mt0 = wm * 2;
    for (int it = 0; it < NCHUNK; it++) {
        if (it + 1 < NCHUNK) {             // async DMA + B prefetch for chunk it+1
            int k0v = (it + 1) << 6;
            const _Float16* Asrc = (k0v < 2048) ? Ahi : Alo;   // segs [hi,hi,lo]
            size_t kp = (size_t)(k0v & 1023);
            dma16(Asrc + abase + kp + ds0 * 16, &Asm[p ^ 1][dmt * 2048 + ds0 * 512]);
            dma16(Asrc + abase + kp + (ds0 + 1) * 16,
                  &Asm[p ^ 1][dmt * 2048 + (ds0 + 1) * 512]);
#pragma unroll
            for (int s = 0; s < 4; s++)
                bnxt[s] = B8[bbase + ((size_t)(it + 1) * 4 + s) * 64];
        }
#pragma unroll
        for (int s = 0; s < 4; s++) {      // lane-linear b128, conflict-free
            half8 a0 = *(const half8*)(&Asm[p][mt0 * 2048 + s * 512 + lane * 8]);
            half8 a1 = *(const half8*)(&Asm[p][(mt0 + 1) * 2048 + s * 512 + lane * 8]);
            acc[0] = __builtin_amdgcn_mfma_f32_32x32x16_f16(a0, bcur[s], acc[0], 0, 0, 0);
            acc[1] = __builtin_amdgcn_mfma_f32_32x32x16_f16(a1, bcur[s], acc[1], 0, 0, 0);
        }
        __syncthreads();                   // drains DMA into p^1 + reads of p
#pragma unroll
        for (int s = 0; s < 4; s++) bcur[s] = bnxt[s];
        p ^= 1;
    }

    // C/D layout (32x32): col=lane&31, row=(reg&3)+8*(reg>>2)+4*(lane>>5)  [m74/m101]
    int c = col0 + wn * 32 + l31;
#pragma unroll
    for (int fi = 0; fi < 2; fi++) {
#pragma unroll
        for (int r = 0; r < 16; r++) {
            int rowid = (r & 3) + 8 * (r >> 2) + 4 * l5;
            int grd = row0 + wm * 64 + fi * 32 + rowid;
            if (grd >= count) continue;
            int g = list ? list[grd] : grd;
            float v = acc[fi][r];
            if (mode == 0) {
                xout[(size_t)g * KDIM + c] = v + bias[c];
            } else {
                v += xbase[(size_t)g * KDIM + c] + flag * flagcol[c] + bias[c];
                v = tanhf(v);
                _Float16 hi = (_Float16)v;
                houthi[(size_t)g * KDIM + c] = hi;
                houtlo[(size_t)g * KDIM + c] = (_Float16)(v - (float)hi);
            }
        }
    }
}

// One wave per active row: halt logit (h = hi+lo), sigmoid, halting state
// machine, tot_h accumulation, next-list compaction.
__global__ __launch_bounds__(256) void halt_kernel(
    const _Float16* __restrict__ Hhi, const _Float16* __restrict__ Hlo,
    const float* __restrict__ W_halt, const float* __restrict__ b_halt,
    const int* __restrict__ list, const int* __restrict__ pcount,
    int* __restrict__ list_next, int* __restrict__ pcount_next,
    float* __restrict__ halt_accum, float* __restrict__ tot_rem,
    float* __restrict__ tot_h, float* __restrict__ steps_out,
    int stepnum, int first) {
    int count = *pcount;
    int wid = threadIdx.x >> 6, lane = threadIdx.x & 63;
    int r = blockIdx.x * 4 + wid;
    if (r >= count) return;
    int row = list[r];
    const _Float16* hh = Hhi + (size_t)row * HID;
    const _Float16* hl = Hlo + (size_t)row * HID;

    float hv[16];
    float dot = 0.f;
#pragma unroll
    for (int q = 0; q < 2; q++) {
        int c = q * 512 + lane * 8;
        half8 h8 = *(const half8*)(hh + c);
        half8 l8 = *(const half8*)(hl + c);
#pragma unroll
        for (int j = 0; j < 8; j++) {
            float v = (float)h8[j] + (float)l8[j];
            hv[q * 8 + j] = v;
            dot += v * W_halt[c + j];
        }
    }
#pragma unroll
    for (int off = 32; off > 0; off >>= 1) dot += __shfl_down(dot, off);

    float combined = 0.f;
    if (lane == 0) {
        float p = 1.f / (1.f + expf(-(dot + b_halt[0])));
        float S = halt_accum[row] + p;
        halt_accum[row] = S;
        tot_rem[row] += p;
        bool ending = (S + p) > 0.99f;      // budget = 1 - PONDER_EPS
        if (ending) {
            combined = p + (1.f - S);
            steps_out[row] = (float)stepnum;
        } else {
            combined = p;
            int idx = atomicAdd(pcount_next, 1);
            list_next[idx] = row;
        }
    }
    combined = __shfl(combined, 0);

    float* th = tot_h + (size_t)row * HID;
#pragma unroll
    for (int q = 0; q < 2; q++) {
        int c = q * 512 + lane * 8;
#pragma unroll
        for (int j = 0; j < 8; j += 4) {
            float4 ov;
            if (first) {
                ov = make_float4(0.f, 0.f, 0.f, 0.f);
            } else {
                ov = *(const float4*)(th + c + j);
            }
            ov.x += combined * hv[q * 8 + j + 0];
            ov.y += combined * hv[q * 8 + j + 1];
            ov.z += combined * hv[q * 8 + j + 2];
            ov.w += combined * hv[q * 8 + j + 3];
            *(float4*)(th + c + j) = ov;
        }
    }
}

// blocks 0..1023: survivors get (1 - halt_accum) * h_final, steps = 16.
// block 1024: ponder reduction.
__global__ __launch_bounds__(256) void epilogue_kernel(
    const _Float16* __restrict__ Hhi, const _Float16* __restrict__ Hlo,
    const int* __restrict__ list, const int* __restrict__ pcount,
    const float* __restrict__ halt_accum, const float* __restrict__ tot_rem,
    float* __restrict__ tot_h, float* __restrict__ steps_out,
    float* __restrict__ ponder) {
    if (blockIdx.x == 1024) {
        __shared__ float red[4];
        int t = threadIdx.x;
        float v = 0.f;
#pragma unroll
        for (int i = 0; i < 16; i++) v += tot_rem[t + i * 256];
#pragma unroll
        for (int off = 32; off > 0; off >>= 1) v += __shfl_down(v, off);
        int lane = t & 63, wid = t >> 6;
        if (lane == 0) red[wid] = v;
        __syncthreads();
        if (t == 0) ponder[0] = (red[0] + red[1] + red[2] + red[3]) * (-0.01f / 4096.f);
        return;
    }
    int count = *pcount;
    int wid = threadIdx.x >> 6, lane = threadIdx.x & 63;
    int r = blockIdx.x * 4 + wid;
    if (r >= count) return;
    int row = list[r];
    float cmb = 1.f - halt_accum[row];
    if (lane == 0) steps_out[row] = 16.f;
    const _Float16* hh = Hhi + (size_t)row * HID;
    const _Float16* hl = Hlo + (size_t)row * HID;
    float* th = tot_h + (size_t)row * HID;
#pragma unroll
    for (int q = 0; q < 2; q++) {
        int c = q * 512 + lane * 8;
        half8 h8 = *(const half8*)(hh + c);
        half8 l8 = *(const half8*)(hl + c);
#pragma unroll
        for (int j = 0; j < 8; j += 4) {
            float4 ov = *(const float4*)(th + c + j);
            ov.x += cmb * ((float)h8[j + 0] + (float)l8[j + 0]);
            ov.y += cmb * ((float)h8[j + 1] + (float)l8[j + 1]);
            ov.z += cmb * ((float)h8[j + 2] + (float)l8[j + 2]);
            ov.w += cmb * ((float)h8[j + 3] + (float)l8[j + 3]);
            *(float4*)(th + c + j) = ov;
        }
    }
}

extern "C" void kernel_launch(void* const* d_in, const int* in_sizes, int n_in,
                              void* d_out, int out_size, void* d_ws, size_t ws_size,
                              hipStream_t stream) {
    const float* inputs = (const float*)d_in[0];
    const float* hidden = (const float*)d_in[1];
    const float* W_ih   = (const float*)d_in[2];
    const float* b_ih   = (const float*)d_in[3];
    const float* W_hh   = (const float*)d_in[4];
    const float* b_hh   = (const float*)d_in[5];
    const float* W_halt = (const float*)d_in[6];
    const float* b_halt = (const float*)d_in[7];
    float* out = (float*)d_out;

    float* ws = (float*)d_ws;
    const size_t NM = (size_t)BATCH * HID;               // 4M elements
    float* xbase = ws;                                   // 4M f32
    _Float16* B3ih = (_Float16*)(xbase + NM);            // HID*KV halfs
    _Float16* B3hh = B3ih + (size_t)HID * KV;
    _Float16* Ahi0 = B3hh + (size_t)HID * KV;            // 4M halfs each
    _Float16* Alo0 = Ahi0 + NM;
    _Float16* Ahi1 = Alo0 + NM;
    _Float16* Alo1 = Ahi1 + NM;
    float* flagcol = (float*)(Alo1 + NM);                // 1024
    float* halt_accum = flagcol + KDIM;                  // 4096
    float* tot_rem = halt_accum + BATCH;                 // 4096
    int* list0 = (int*)(tot_rem + BATCH);                // 4096
    int* list1 = list0 + BATCH;                          // 4096
    int* counts = list1 + BATCH;                         // 16

    _Float16* Ahi[2] = {Ahi0, Ahi1};
    _Float16* Alo[2] = {Alo0, Alo1};
    int* lists[2] = {list0, list1};

    float* tot_h = out;
    float* ponder = out + NM;
    float* steps_out = ponder + 1;

    // setup: pack B frags, split inputs -> buf1 (dead after x_base), hidden -> buf0
    setup_kernel<<<16384, 256, 0, stream>>>(W_ih, W_hh, inputs, hidden,
                                            B3ih, B3hh, Ahi1, Alo1, Ahi0, Alo0,
                                            flagcol, list0, counts, halt_accum, tot_rem);

    // x_base = inputs @ W_ih[:, :-1].T + b_ih
    mfma_step_kernel<<<dim3(32, 8), 512, 0, stream>>>(
        Ahi1, Alo1, B3ih, b_ih, nullptr, nullptr, 0.f, nullptr, nullptr,
        nullptr, nullptr, xbase, 0);

    for (int t = 0; t < NSTEP; t++) {
        mfma_step_kernel<<<dim3(32, 8), 512, 0, stream>>>(
            Ahi[t & 1], Alo[t & 1], B3hh, b_hh, xbase, flagcol,
            (t == 0) ? 1.f : 0.f, lists[t & 1], counts + t,
            Ahi[(t + 1) & 1], Alo[(t + 1) & 1], nullptr, 1);
        halt_kernel<<<1024, 256, 0, stream>>>(Ahi[(t + 1) & 1], Alo[(t + 1) & 1],
                                              W_halt, b_halt,
                                              lists[t & 1], counts + t,
                                              lists[(t + 1) & 1], counts + t + 1,
                                              halt_accum, tot_rem, tot_h, steps_out,
                                              t + 1, (t == 0) ? 1 : 0);
    }
    epilogue_kernel<<<1025, 256, 0, stream>>>(Ahi[0], Alo[0], lists[1], counts + 15,
                                              halt_accum, tot_rem, tot_h, steps_out, ponder);
}